// Round 11
// baseline (42.983 us; speedup 1.0000x reference)
//
#include <hip/hip_runtime.h>

#define TT   512
#define BB   4
#define OUTL 261632        // per-batch trimmed output length

// padded float2 slot in the per-column Z buffer
#define ZP(k) ((k) + ((k) >> 3))

__device__ __forceinline__ float2 cmul(float2 a, float2 w) {
    return make_float2(a.x * w.x - a.y * w.y, a.x * w.y + a.y * w.x);
}

// radix-4 DIT butterfly (inverse, +i), twiddles w1, w1^2, w1^3 (r3-proven)
__device__ __forceinline__ void bf4(const float2 a[4], float2 o[4], float2 w1) {
    float2 w2 = make_float2(w1.x * w1.x - w1.y * w1.y, 2.f * w1.x * w1.y);
    float2 w3 = cmul(w1, w2);
    float t0r = a[0].x + a[2].x, t0i = a[0].y + a[2].y;
    float t1r = a[0].x - a[2].x, t1i = a[0].y - a[2].y;
    float t2r = a[1].x + a[3].x, t2i = a[1].y + a[3].y;
    float t3r = a[3].y - a[1].y, t3i = a[1].x - a[3].x;   // i*(a1-a3)
    o[0] = make_float2(t0r + t2r, t0i + t2i);
    o[1] = cmul(make_float2(t1r + t3r, t1i + t3i), w1);
    o[2] = cmul(make_float2(t0r - t2r, t0i - t2i), w2);
    o[3] = cmul(make_float2(t1r - t3r, t1i - t3i), w3);
}

// ---- tr_k: X[b][f][t][2] -> Xt[(b*512+t)][f] (float2), 64x64 LDS tiles ----
__global__ __launch_bounds__(256) void tr_k(const float* __restrict__ X,
                                            float* __restrict__ Xt) {
    __shared__ float2 tile[64][65];
    const int f0 = blockIdx.x * 64;
    const int t0 = blockIdx.y * 64;
    const int b  = blockIdx.z;
    const int tid = threadIdx.x;
    #pragma unroll
    for (int it = 0; it < 8; it++) {
        int idx = it * 256 + tid;          // 0..2047
        int fi = idx >> 5;                 // 0..63
        int tj = (idx & 31) * 2;           // 0..62
        const float4 v = *reinterpret_cast<const float4*>(
            X + (((size_t)(b * 2048 + f0 + fi)) * 512 + t0 + tj) * 2);
        tile[fi][tj]     = make_float2(v.x, v.y);
        tile[fi][tj + 1] = make_float2(v.z, v.w);
    }
    __syncthreads();
    #pragma unroll
    for (int it = 0; it < 8; it++) {
        int idx = it * 256 + tid;
        int ti = idx >> 5;
        int fj = (idx & 31) * 2;
        int c  = b * 512 + t0 + ti;
        float2 p = tile[fj][ti];
        float2 q = tile[fj + 1][ti];
        *reinterpret_cast<float4*>(Xt + ((size_t)c * 2048 + f0 + fj) * 2) =
            make_float4(p.x, p.y, q.x, q.y);
    }
}

// mid stage of the 1024-pt radix-4 Stockham (stride SS), on padded Z buffer
template<int SS>
__device__ __forceinline__ void mid1024(float2* Zg, int u,
                                        const float* twc, const float* tws) {
    float2 a[4], o[4];
    #pragma unroll
    for (int q = 0; q < 4; q++) a[q] = Zg[ZP(u + 256 * q)];
    __syncthreads();
    const int mA = u & ~(SS - 1), rA = u & (SS - 1);
    bf4(a, o, make_float2(twc[2 * mA], tws[2 * mA]));   // W_1024^mA
    const int j = 4 * mA + rA;
    #pragma unroll
    for (int k = 0; k < 4; k++) Zg[ZP(j + SS * k)] = o[k];
    __syncthreads();
}

// ---- fused iSTFT: one block = ONE column (256 thr, 9.2KB LDS, 8 blocks/CU).
//      1024-pt packed real-output inverse FFT, window, all-atomic OLA. ----
__global__ __launch_bounds__(256, 8) void istft_k(const float* __restrict__ Xt,
                                                  const float* __restrict__ kc,
                                                  const float* __restrict__ ks,
                                                  const float* __restrict__ win,
                                                  float* __restrict__ out) {
    __shared__ float2 Zg[1152];            // 9.2 KB; reused as the frame

    const int S = blockIdx.x;              // 0..2047
    const int c = ((S & 7) << 8) | (S >> 3);   // XCD x owns columns [256x,256x+256)
    const int b = c >> 9;
    const int t = c & 511;
    const int u = threadIdx.x;             // 0..255
    const float2* Xc = reinterpret_cast<const float2*>(Xt) + (size_t)c * 2048;
    const float* twc = kc + 2048;          // cos(2*pi*m/2048) (kernel row n=1)
    const float* tws = ks + 2048;          // +sin (inverse)

    // ---- pack (X -> Z) fused with stage A (s=1) ----
    float2 a[4], o[4];
    #pragma unroll
    for (int l = 0; l < 4; l++) {
        int k = u + 256 * l;               // 0..1023
        float2 Xk  = Xc[k];
        float2 Xrv = Xc[(2048 - k) & 2047];
        float2 Xk1 = Xc[1024 + k];
        float2 Xm1 = Xc[1024 - k];
        float2 Yk  = make_float2(0.5f * (Xk.x + Xrv.x),  0.5f * (Xk.y - Xrv.y));
        float2 Yk1 = make_float2(0.5f * (Xk1.x + Xm1.x), 0.5f * (Xk1.y - Xm1.y));
        float2 A = make_float2(Yk.x + Yk1.x, Yk.y + Yk1.y);
        float2 D = make_float2(Yk.x - Yk1.x, Yk.y - Yk1.y);
        float2 Bv = cmul(D, make_float2(twc[k], tws[k]));   // e^{2pi i k/2048}
        a[l] = make_float2(A.x - Bv.y, A.y + Bv.x);         // Z[k] = A + iB
    }
    bf4(a, o, make_float2(twc[2 * u], tws[2 * u]));         // W_1024^u
    #pragma unroll
    for (int k = 0; k < 4; k++) Zg[ZP(4 * u + k)] = o[k];
    __syncthreads();

    // ---- stages s=4,16,64 ----
    mid1024<4>(Zg, u, twc, tws);
    mid1024<16>(Zg, u, twc, tws);
    mid1024<64>(Zg, u, twc, tws);

    // ---- stage s=256 (twiddle=1) + reconstruct + window -> frame ----
    float2 e[4], z[4];
    #pragma unroll
    for (int q = 0; q < 4; q++) e[q] = Zg[ZP(u + 256 * q)];
    __syncthreads();
    bf4(e, z, make_float2(1.f, 0.f));
    float* fr = reinterpret_cast<float*>(Zg);
    #pragma unroll
    for (int k = 0; k < 4; k++) {
        int m = u + 256 * k;               // z[m]: x[2m]=Re, x[2m+1]=Im
        fr[2 * m]     = z[k].x * win[2 * m];
        fr[2 * m + 1] = z[k].y * win[2 * m + 1];
    }
    __syncthreads();

    // ---- OLA (all-atomic, coalesced, 4 writers/sample) ----
    const bool interior = (t >= 3) && (t <= 508);
    float invw0 = 0.f, invw1 = 0.f;
    {
        float s0 = 0.f, s1 = 0.f;
        #pragma unroll
        for (int kk = 0; kk < 4; kk++) {
            float w0 = win[u + 512 * kk];         // rr = u
            float w1 = win[((u + 256) & 511) + 512 * kk];   // rr = u+256
            s0 += w0 * w0; s1 += w1 * w1;
        }
        invw0 = 1.0f / (2048.0f * s0);
        invw1 = 1.0f / (2048.0f * s1);
    }
    float* outb = out + (size_t)b * OUTL;
    #pragma unroll
    for (int q = 0; q < 8; q++) {
        int n  = u + 256 * q;              // 0..2047
        int j  = t * 512 + n;
        int jp = j - 1024;
        if (jp < 0 || jp >= OUTL) continue;
        float y = fr[n];
        if (interior) {
            y *= (q & 1) ? invw1 : invw0;
        } else {
            int tb = j >> 9, rr = j & 511;
            float s = 0.f;
            #pragma unroll
            for (int kk = 0; kk < 4; kk++) {
                int tt = tb - kk;
                if (tt >= 0 && tt < TT) { float w = win[rr + (kk << 9)]; s += w * w; }
            }
            y *= (1.0f / 2048.0f);
            if (s > 1e-10f) y /= s;
        }
        atomicAdd(outb + jp, y);
    }
}

extern "C" void kernel_launch(void* const* d_in, const int* in_sizes, int n_in,
                              void* d_out, int out_size, void* d_ws, size_t ws_size,
                              hipStream_t stream) {
    const float* X  = (const float*)d_in[0];
    const float* kc = (const float*)d_in[1];
    const float* ks = (const float*)d_in[2];
    const float* w  = (const float*)d_in[3];
    float* out = (float*)d_out;
    float* Xt  = (float*)d_ws;                 // 2048*2048 float2 = 33.6 MB

    hipMemsetAsync(out, 0, (size_t)out_size * sizeof(float), stream);
    tr_k<<<dim3(32, 8, 4), dim3(256), 0, stream>>>(X, Xt);
    istft_k<<<dim3(BB * TT), dim3(256), 0, stream>>>(Xt, kc, ks, w, out);
}